// Round 4
// baseline (622.559 us; speedup 1.0000x reference)
//
#include <hip/hip_runtime.h>
#include <hip/hip_bf16.h>
#include <math.h>

// ---------------------------------------------------------------------------
// GRU-like cell. B=64, T=512, D=512, H=1024 (fp32).
// Round 5:
//   * GEMM: faithful m201-style fine-grained phase schedule. 4 phases per
//     K-step; each phase = {1 half-tile stage issue (2 gl_lds) || 4-8
//     ds_read_b128} -> s_barrier -> lgkmcnt(0)+sched_barrier(0) ->
//     setprio(1) -> 16-32 MFMA -> setprio(0) -> s_barrier. Staging
//     staggered (A halves early = HBM-latency cover 3-4 phases; B halves
//     late = L2-resident), one vmcnt(0) per K-step at step end (optimal
//     for dbuf=2). Short read bursts tightly alternating with MFMA bursts
//     keep the 2 waves/SIMD anti-phased -> LDS and MFMA pipes overlap
//     (m196/m201 mechanism) instead of convoying (rounds 2/3: 8280 cy/step
//     vs ~4000 envelope).
//   * Scan/converts unchanged from round 4 (rcp+NR sigmoid-form scan).
// Precision: 3-term fp16 split GEMM and fp32 scan unchanged.
// ---------------------------------------------------------------------------

#define M_DIM 32768   // B*T
#define K_DIM 512     // D
#define H_DIM 1024
#define N3    3072    // 3*H

typedef _Float16 half8v __attribute__((ext_vector_type(8)));
typedef _Float16 half4v __attribute__((ext_vector_type(4)));
typedef float f32x4 __attribute__((ext_vector_type(4)));

__device__ __forceinline__ f32x4 mfma16(half8v a, half8v b, f32x4 c) {
    return __builtin_amdgcn_mfma_f32_16x16x32_f16(a, b, c, 0, 0, 0);
}

__device__ __forceinline__ void load_lds16(const void* g, void* l) {
    __builtin_amdgcn_global_load_lds(
        (const __attribute__((address_space(1))) void*)g,
        (__attribute__((address_space(3))) void*)l, 16, 0, 0);
}

// ---------------------------------------------------------------------------
// Conversion: x [M,K] fp32 -> xhi/xlo fp16 (same layout), via float4.
// ---------------------------------------------------------------------------
__global__ __launch_bounds__(256) void convert_x(
    const float4* __restrict__ x4, half4v* __restrict__ hi4,
    half4v* __restrict__ lo4, int n4)
{
    int i = blockIdx.x * 256 + threadIdx.x;
    if (i >= n4) return;
    float4 v = x4[i];
    half4v h, lo;
    h.x = (_Float16)v.x; lo.x = (_Float16)(v.x - (float)h.x);
    h.y = (_Float16)v.y; lo.y = (_Float16)(v.y - (float)h.y);
    h.z = (_Float16)v.z; lo.z = (_Float16)(v.z - (float)h.z);
    h.w = (_Float16)v.w; lo.w = (_Float16)(v.w - (float)h.w);
    hi4[i] = h; lo4[i] = lo;
}

// Weights [K,1024] fp32 -> transposed hi/lo fp16 [3][1024][K].
__global__ __launch_bounds__(256) void convert_wt(
    const float* __restrict__ kz, const float* __restrict__ kr,
    const float* __restrict__ kh, _Float16* __restrict__ wth,
    _Float16* __restrict__ wtl)
{
    int gid = blockIdx.x * 256 + threadIdx.x;   // 3*1024*512
    int k = gid & (K_DIM - 1);
    int n = (gid >> 9) & (H_DIM - 1);
    int wsel = gid >> 19;                        // uniform per block
    const float* s = (wsel == 0) ? kz : ((wsel == 1) ? kr : kh);
    float v = s[(size_t)k * H_DIM + n];
    _Float16 h = (_Float16)v;
    wth[gid] = h;
    wtl[gid] = (_Float16)(v - (float)h);
}

// ---------------------------------------------------------------------------
// MFMA GEMM: C[M,3072] = A[M,512] * Bt[3072,512]^T, fp16 3-term split.
// 256x256 block tile, 512 threads (8 waves, 2x4), per-wave 128x64 output.
// BK=32. LDS: 2 x (A 32KB + B 32KB) = 128 KiB, rows = [64B hi | 64B lo],
// XOR-swizzled (inverse-swizzled global source, swizzled ds_read).
// Per K-step, 4 phases (each: stage-issue || ds_read -> bar -> lgkm0 ->
// setprio1 MFMA setprio0 -> bar):
//   ph0: stage A-top(t+1); read afh,bfh (8);  16 MFMA  hh  (mi0-3)
//   ph1: stage A-bot(t+1); read afl,bfl (8);  32 MFMA  hl,lh (mi0-3)
//   ph2: stage B-top(t+1); read afh2 (4);     16 MFMA  hh  (mi4-7)
//   ph3: stage B-bot(t+1); read afl2 (4);     32 MFMA  hl,lh (mi4-7)
//        + vmcnt(0) before final barrier (worst half-tile cover >= 1 phase)
// ---------------------------------------------------------------------------
__global__ __launch_bounds__(512, 2) void gemm_mfma_split(
    const _Float16* __restrict__ Ahi, const _Float16* __restrict__ Alo,
    const _Float16* __restrict__ Bthi, const _Float16* __restrict__ Btlo,
    float* __restrict__ XZ, float* __restrict__ XR, float* __restrict__ OUT)
{
    __shared__ _Float16 AT[2][256 * 64];   // 32 KB per buffer
    __shared__ _Float16 BT[2][256 * 64];

    const int tid = threadIdx.x;
    const int w = tid >> 6, l = tid & 63;
    const int l15 = l & 15, quad = l >> 4;
    const int wr = w >> 2;          // 0..1  (M groups of 128)
    const int wc = w & 3;           // 0..3  (N groups of 64)

    // XCD-aware bijective remap: 1536 blocks = 8 XCDs * 192.
    const int nblk = blockIdx.x;
    const int swz = (nblk & 7) * 192 + (nblk >> 3);
    const int by = swz / 12;
    const int bx = swz - by * 12;
    const long m0 = (long)by * 256;
    const long n0 = (long)bx * 256;

    f32x4 acc[8][4] = {};

    // Staging: per matrix 2048 16B slots per K-step; 4 per thread.
    // slot s -> row r=s>>3, unit u=s&7; source byte within row =
    // (u ^ (r&7))*16 (inverse swizzle); LDS dest linear at s*16.
    // gA[0..1] cover rows 0..127 (A-top), gA[2..3] rows 128..255 (A-bot);
    // same split for gB.
    const _Float16* gA[4]; const _Float16* gB[4];
    int lofs[4];
#pragma unroll
    for (int i = 0; i < 4; ++i) {
        const int s = i * 512 + tid;
        const int r = s >> 3;
        const int o2 = ((s & 7) ^ (r & 7)) << 4;
        const int part  = o2 >> 6;                 // 0 = hi, 1 = lo
        const int khalf = ((o2 >> 4) & 3) * 8;
        gA[i] = (part ? Alo : Ahi) + (m0 + r) * K_DIM + khalf;
        gB[i] = (part ? Btlo : Bthi) + (n0 + r) * K_DIM + khalf;
        lofs[i] = (i * 512 + (w << 6)) * 8;        // wave-uniform halfs
    }

    // Prologue: stage K-step 0 into buffer 0.
#pragma unroll
    for (int i = 0; i < 4; ++i) { load_lds16(gA[i], &AT[0][lofs[i]]); gA[i] += 32; }
#pragma unroll
    for (int i = 0; i < 4; ++i) { load_lds16(gB[i], &BT[0][lofs[i]]); gB[i] += 32; }
    asm volatile("s_waitcnt vmcnt(0)" ::: "memory");
    __builtin_amdgcn_s_barrier();

    for (int t = 0; t < 16; ++t) {
        const int cur = t & 1;
        const _Float16* at = &AT[cur][0];
        const _Float16* bt = &BT[cur][0];
        _Float16* an = &AT[cur ^ 1][0];
        _Float16* bn = &BT[cur ^ 1][0];
        const bool pf = (t + 1) < 16;

        // =============== phase 0: A-top stage | afh,bfh | hh(mi0-3) ======
        if (pf) {
            load_lds16(gA[0], an + lofs[0]); gA[0] += 32;
            load_lds16(gA[1], an + lofs[1]); gA[1] += 32;
        }
        half8v bfh[4], bfl[4], afh[4], afl[4];
#pragma unroll
        for (int ni = 0; ni < 4; ++ni) {
            const int r = wc * 64 + ni * 16 + l15;
            const int off = (quad ^ (r & 7)) * 8;
            bfh[ni] = *(const half8v*)&bt[r * 64 + off];
        }
#pragma unroll
        for (int mi = 0; mi < 4; ++mi) {
            const int r = wr * 128 + mi * 16 + l15;
            const int off = (quad ^ (r & 7)) * 8;
            afh[mi] = *(const half8v*)&at[r * 64 + off];
        }
        __builtin_amdgcn_s_barrier();
        asm volatile("s_waitcnt lgkmcnt(0)" ::: "memory");
        __builtin_amdgcn_sched_barrier(0);
        __builtin_amdgcn_s_setprio(1);
#pragma unroll
        for (int mi = 0; mi < 4; ++mi)
#pragma unroll
            for (int ni = 0; ni < 4; ++ni)
                acc[mi][ni] = mfma16(afh[mi], bfh[ni], acc[mi][ni]);
        __builtin_amdgcn_s_setprio(0);
        __builtin_amdgcn_s_barrier();

        // =============== phase 1: A-bot stage | afl,bfl | hl,lh(mi0-3) ===
        if (pf) {
            load_lds16(gA[2], an + lofs[2]); gA[2] += 32;
            load_lds16(gA[3], an + lofs[3]); gA[3] += 32;
        }
#pragma unroll
        for (int ni = 0; ni < 4; ++ni) {
            const int r = wc * 64 + ni * 16 + l15;
            const int off = (quad ^ (r & 7)) * 8;
            bfl[ni] = *(const half8v*)&bt[r * 64 + (off ^ 32)];
        }
#pragma unroll
        for (int mi = 0; mi < 4; ++mi) {
            const int r = wr * 128 + mi * 16 + l15;
            const int off = (quad ^ (r & 7)) * 8;
            afl[mi] = *(const half8v*)&at[r * 64 + (off ^ 32)];
        }
        __builtin_amdgcn_s_barrier();
        asm volatile("s_waitcnt lgkmcnt(0)" ::: "memory");
        __builtin_amdgcn_sched_barrier(0);
        __builtin_amdgcn_s_setprio(1);
#pragma unroll
        for (int mi = 0; mi < 4; ++mi)
#pragma unroll
            for (int ni = 0; ni < 4; ++ni)
                acc[mi][ni] = mfma16(afh[mi], bfl[ni], acc[mi][ni]);
#pragma unroll
        for (int mi = 0; mi < 4; ++mi)
#pragma unroll
            for (int ni = 0; ni < 4; ++ni)
                acc[mi][ni] = mfma16(afl[mi], bfh[ni], acc[mi][ni]);
        __builtin_amdgcn_s_setprio(0);
        __builtin_amdgcn_s_barrier();

        // =============== phase 2: B-top stage | afh2 | hh(mi4-7) =========
        if (pf) {
            load_lds16(gB[0], bn + lofs[0]); gB[0] += 32;
            load_lds16(gB[1], bn + lofs[1]); gB[1] += 32;
        }
        half8v afh2[4], afl2[4];
#pragma unroll
        for (int mi = 0; mi < 4; ++mi) {
            const int r = wr * 128 + 64 + mi * 16 + l15;
            const int off = (quad ^ (r & 7)) * 8;
            afh2[mi] = *(const half8v*)&at[r * 64 + off];
        }
        __builtin_amdgcn_s_barrier();
        asm volatile("s_waitcnt lgkmcnt(0)" ::: "memory");
        __builtin_amdgcn_sched_barrier(0);
        __builtin_amdgcn_s_setprio(1);
#pragma unroll
        for (int mi = 0; mi < 4; ++mi)
#pragma unroll
            for (int ni = 0; ni < 4; ++ni)
                acc[4 + mi][ni] = mfma16(afh2[mi], bfh[ni], acc[4 + mi][ni]);
        __builtin_amdgcn_s_setprio(0);
        __builtin_amdgcn_s_barrier();

        // =============== phase 3: B-bot stage | afl2 | hl,lh(mi4-7) ======
        if (pf) {
            load_lds16(gB[2], bn + lofs[2]); gB[2] += 32;
            load_lds16(gB[3], bn + lofs[3]); gB[3] += 32;
        }
#pragma unroll
        for (int mi = 0; mi < 4; ++mi) {
            const int r = wr * 128 + 64 + mi * 16 + l15;
            const int off = (quad ^ (r & 7)) * 8;
            afl2[mi] = *(const half8v*)&at[r * 64 + (off ^ 32)];
        }
        __builtin_amdgcn_s_barrier();
        asm volatile("s_waitcnt lgkmcnt(0)" ::: "memory");
        __builtin_amdgcn_sched_barrier(0);
        __builtin_amdgcn_s_setprio(1);
#pragma unroll
        for (int mi = 0; mi < 4; ++mi)
#pragma unroll
            for (int ni = 0; ni < 4; ++ni)
                acc[4 + mi][ni] = mfma16(afh2[mi], bfl[ni], acc[4 + mi][ni]);
#pragma unroll
        for (int mi = 0; mi < 4; ++mi)
#pragma unroll
            for (int ni = 0; ni < 4; ++ni)
                acc[4 + mi][ni] = mfma16(afl2[mi], bfh[ni], acc[4 + mi][ni]);
        __builtin_amdgcn_s_setprio(0);
        // Drain next-step staging (A halves: 3-4 phases of cover; B-bot:
        // ~1 phase) and release buffers for the swap.
        asm volatile("s_waitcnt vmcnt(0)" ::: "memory");
        __builtin_amdgcn_s_barrier();
    }

    // Epilogue: C/D layout col=lane&15, row=quad*4+i.
    float* dst = (bx < 4) ? XZ : ((bx < 8) ? XR : OUT);
    const long nl = (long)(bx & 3) * 256 + wc * 64 + l15;
#pragma unroll
    for (int mi = 0; mi < 8; ++mi) {
        const long m = m0 + wr * 128 + mi * 16 + quad * 4;
#pragma unroll
        for (int ni = 0; ni < 4; ++ni) {
            float* p = dst + m * H_DIM + nl + ni * 16;
#pragma unroll
            for (int i = 0; i < 4; ++i)
                p[(long)i * H_DIM] = acc[mi][ni][i];
        }
    }
}

// ---------------------------------------------------------------------------
// Fallback fp32 GEMM (round 0)
// ---------------------------------------------------------------------------
#define BM 128
#define BN 128
#define BK 8
__global__ __launch_bounds__(256) void gemm_f32(
    const float* __restrict__ A, const float* __restrict__ B,
    float* __restrict__ C, int M, int N, int K)
{
    __shared__ float As[BK][BM];
    __shared__ float Bs[BK][BN];
    const int tid = threadIdx.x;
    const int bm = blockIdx.y * BM, bn = blockIdx.x * BN;
    const int tx = tid & 15, ty = tid >> 4;
    float acc[8][8];
#pragma unroll
    for (int i = 0; i < 8; i++)
#pragma unroll
        for (int j = 0; j < 8; j++) acc[i][j] = 0.f;
    const int a_row = tid >> 1, a_k = (tid & 1) * 4;
    const int b_row = tid >> 5, b_col = (tid & 31) * 4;
    const float* Aptr = A + (size_t)(bm + a_row) * K + a_k;
    const float* Bptr = B + (size_t)b_row * N + bn + b_col;
    for (int k0 = 0; k0 < K; k0 += BK) {
        float4 av = *(const float4*)(Aptr + k0);
        float4 bv = *(const float4*)(Bptr + (size_t)k0 * N);
        As[a_k + 0][a_row] = av.x; As[a_k + 1][a_row] = av.y;
        As[a_k + 2][a_row] = av.z; As[a_k + 3][a_row] = av.w;
        *(float4*)&Bs[b_row][b_col] = bv;
        __syncthreads();
#pragma unroll
        for (int kk = 0; kk < BK; kk++) {
            float4 a0 = *(const float4*)&As[kk][ty * 8];
            float4 a1 = *(const float4*)&As[kk][ty * 8 + 4];
            float4 b0 = *(const float4*)&Bs[kk][tx * 8];
            float4 b1 = *(const float4*)&Bs[kk][tx * 8 + 4];
            float a[8] = {a0.x, a0.y, a0.z, a0.w, a1.x, a1.y, a1.z, a1.w};
            float b[8] = {b0.x, b0.y, b0.z, b0.w, b1.x, b1.y, b1.z, b1.w};
#pragma unroll
            for (int i = 0; i < 8; i++)
#pragma unroll
                for (int j = 0; j < 8; j++)
                    acc[i][j] = fmaf(a[i], b[j], acc[i][j]);
        }
        __syncthreads();
    }
    float* Cptr = C + (size_t)(bm + ty * 8) * N + bn + tx * 8;
#pragma unroll
    for (int i = 0; i < 8; i++) {
        float4 c0 = {acc[i][0], acc[i][1], acc[i][2], acc[i][3]};
        float4 c1 = {acc[i][4], acc[i][5], acc[i][6], acc[i][7]};
        *(float4*)(Cptr + (size_t)i * N)     = c0;
        *(float4*)(Cptr + (size_t)i * N + 4) = c1;
    }
}

// ---------------------------------------------------------------------------
// Scan, 16-deep prefetch. OUT holds xh on entry, h_t on exit.
// Gates in sigmoid form; divisions via v_rcp + 1 Newton step.
// ---------------------------------------------------------------------------
__device__ __forceinline__ float vrcp_nr(float d) {
    float r = __builtin_amdgcn_rcpf(d);
    return r * fmaf(-d, r, 2.0f);     // Newton: r*(2 - d*r)
}

__global__ __launch_bounds__(256) void scan_kernel(
    const float* __restrict__ XZ, const float* __restrict__ XR,
    float* __restrict__ OUT,
    const float* __restrict__ mz, const float* __restrict__ mr,
    const float* __restrict__ br, const float* __restrict__ bz)
{
    const int gid = blockIdx.x * blockDim.x + threadIdx.x;
    const int b = gid >> 10;          // H=1024
    const int h = gid & (H_DIM - 1);

    const float mzK = -mz[h];
    const float mrK = -2.0f * mr[h];
    const float bzK = -bz[h];
    const float brK = -2.0f * br[h];
    float hs = 0.f;
    size_t idx = (size_t)b * 512 * H_DIM + h;

    float cz[16], cr[16], ch[16];
#pragma unroll
    for (int j = 0; j < 16; ++j) {
        cz[j] = bzK - XZ[idx + (size_t)j * H_DIM];
        cr[j] = fmaf(-2.0f, XR[idx + (size_t)j * H_DIM], brK);
        ch[j] = -2.0f * OUT[idx + (size_t)j * H_DIM];
    }
    for (int t0 = 0; t0 < 512; t0 += 16) {
        float nz[16], nr[16], nh[16];
        const bool more = (t0 + 16) < 512;
        const size_t nidx = idx + 16ul * H_DIM;
        if (more) {
#pragma unroll
            for (int j = 0; j < 16; ++j) {
                nz[j] = XZ[nidx + (size_t)j * H_DIM];
                nr[j] = XR[nidx + (size_t)j * H_DIM];
                nh[j] = OUT[nidx + (size_t)j * H_DIM];
            }
        }
#pragma unroll
        for (int j = 0; j < 16; ++j) {
            const float u1   = fmaf(hs, mrK, cr[j]);
            const float uz   = fmaf(hs, mzK, cz[j]);
            const float hsK2 = -4.0f * hs;
            const float e1 = __expf(u1);
            const float s1 = vrcp_nr(e1 + 1.0f);
            const float ez = __expf(uz);
            const float sz = vrcp_nr(ez + 1.0f);
            const float u2 = fmaf(s1, hsK2, ch[j]);
            const float e2 = __expf(u2);
            const float s2 = vrcp_nr(e2 + 1.0f);
            const float th = fmaf(2.0f, s2, -1.0f);
            const float hn = fmaf(sz, hs - th, th);
            OUT[idx + (size_t)j * H_DIM] = hn;
            hs = hn;
        }
        idx = nidx;
        if (more) {
#pragma unroll
            for (int j = 0; j < 16; ++j) {
                cz[j] = bzK - nz[j];
                cr[j] = fmaf(-2.0f, nr[j], brK);
                ch[j] = -2.0f * nh[j];
            }
        }
    }
}

// ---------------------------------------------------------------------------
extern "C" void kernel_launch(void* const* d_in, const int* in_sizes, int n_in,
                              void* d_out, int out_size, void* d_ws, size_t ws_size,
                              hipStream_t stream) {
    const float* x  = (const float*)d_in[0];
    const float* kz = (const float*)d_in[1];
    const float* kr = (const float*)d_in[2];
    const float* kh = (const float*)d_in[3];
    const float* mz = (const float*)d_in[4];
    const float* mr = (const float*)d_in[5];
    const float* br = (const float*)d_in[6];
    const float* bz = (const float*)d_in[7];
    float* out = (float*)d_out;

    char* ws = (char*)d_ws;
    float* XZ = (float*)ws;                              // 128 MiB
    float* XR = (float*)(ws + 134217728ul);              // 128 MiB
    _Float16* XHI = (_Float16*)(ws + 268435456ul);       // 32 MiB
    _Float16* XLO = (_Float16*)(ws + 301989888ul);       // 32 MiB
    _Float16* WTH = (_Float16*)(ws + 335544320ul);       // 3 MiB
    _Float16* WTL = (_Float16*)(ws + 338690048ul);       // 3 MiB
    const size_t need = 341835776ul;

    if (ws_size >= need) {
        int n4 = M_DIM * K_DIM / 4;                      // 4.19M
        convert_x<<<n4 / 256, 256, 0, stream>>>(
            (const float4*)x, (half4v*)XHI, (half4v*)XLO, n4);
        convert_wt<<<(3 * H_DIM * K_DIM) / 256, 256, 0, stream>>>(
            kz, kr, kh, WTH, WTL);
        gemm_mfma_split<<<1536, 512, 0, stream>>>(
            XHI, XLO, WTH, WTL, XZ, XR, out);
    } else {
        dim3 grid(H_DIM / BN, M_DIM / BM);
        gemm_f32<<<grid, 256, 0, stream>>>(x, kz, XZ,  M_DIM, H_DIM, K_DIM);
        gemm_f32<<<grid, 256, 0, stream>>>(x, kr, XR,  M_DIM, H_DIM, K_DIM);
        gemm_f32<<<grid, 256, 0, stream>>>(x, kh, out, M_DIM, H_DIM, K_DIM);
    }

    scan_kernel<<<(64 * H_DIM) / 256, 256, 0, stream>>>(
        XZ, XR, out, mz, mr, br, bz);
}

// Round 5
// 601.597 us; speedup vs baseline: 1.0348x; 1.0348x over previous
//
#include <hip/hip_runtime.h>
#include <hip/hip_bf16.h>
#include <math.h>

// ---------------------------------------------------------------------------
// GRU-like cell. B=64, T=512, D=512, H=1024 (fp32).
// Round 6:
//   * GEMM reverted to the round-0 structure (128x128 tile, 4 waves, simple
//     2D grid) -- best measured (303 us) across 5 structure attempts; all
//     phase-schedule refinements regressed and are abandoned.
//   * NEW: intermediates xz/xr/xh stored TRANSPOSED [b][h][t] by the GEMM
//     epilogue (C-fragment rows are t-contiguous -> 16 float4 stores/thread).
//     Scan reads become contiguous per-thread streams: 12 float4 loads per
//     32-step chunk, immediate-offset addressing, 32-deep prefetch. Fixes
//     the scan's latency-bound profile (est. ~215 us vs 81 us BW floor).
//   * Scan per-step math BIT-IDENTICAL to round 3 (verified absmax 2^-8).
//   * convert_wt rewritten as LDS-tiled transpose (old version read
//     stride-4KB columns, fully uncoalesced).
// Precision: 3-term fp16 split GEMM and fp32 scan math unchanged.
// ---------------------------------------------------------------------------

#define M_DIM 32768   // B*T
#define K_DIM 512     // D
#define H_DIM 1024
#define N3    3072    // 3*H

typedef _Float16 half8v __attribute__((ext_vector_type(8)));
typedef _Float16 half4v __attribute__((ext_vector_type(4)));
typedef float f32x4 __attribute__((ext_vector_type(4)));

__device__ __forceinline__ f32x4 mfma16(half8v a, half8v b, f32x4 c) {
    return __builtin_amdgcn_mfma_f32_16x16x32_f16(a, b, c, 0, 0, 0);
}

__device__ __forceinline__ void load_lds16(const void* g, void* l) {
    __builtin_amdgcn_global_load_lds(
        (const __attribute__((address_space(1))) void*)g,
        (__attribute__((address_space(3))) void*)l, 16, 0, 0);
}

// ---------------------------------------------------------------------------
// Conversion: x [M,K] fp32 -> xhi/xlo fp16 (same layout), via float4.
// ---------------------------------------------------------------------------
__global__ __launch_bounds__(256) void convert_x(
    const float4* __restrict__ x4, half4v* __restrict__ hi4,
    half4v* __restrict__ lo4, int n4)
{
    int i = blockIdx.x * 256 + threadIdx.x;
    if (i >= n4) return;
    float4 v = x4[i];
    half4v h, lo;
    h.x = (_Float16)v.x; lo.x = (_Float16)(v.x - (float)h.x);
    h.y = (_Float16)v.y; lo.y = (_Float16)(v.y - (float)h.y);
    h.z = (_Float16)v.z; lo.z = (_Float16)(v.z - (float)h.z);
    h.w = (_Float16)v.w; lo.w = (_Float16)(v.w - (float)h.w);
    hi4[i] = h; lo4[i] = lo;
}

// ---------------------------------------------------------------------------
// Weights [K,1024] fp32 -> transposed hi/lo fp16 [3][1024][512].
// LDS-tiled 64x64 transpose: coalesced float4 reads AND coalesced half4
// writes (old version read stride-4KB columns).
// ---------------------------------------------------------------------------
__global__ __launch_bounds__(256) void convert_wt_t(
    const float* __restrict__ kz, const float* __restrict__ kr,
    const float* __restrict__ kh, _Float16* __restrict__ wth,
    _Float16* __restrict__ wtl)
{
    __shared__ float lds[64][65];
    const int bid = blockIdx.x;          // 3 * 8 * 16 = 384
    const int w = bid >> 7;              // weight select
    const int rem = bid & 127;
    const int k0 = (rem >> 4) * 64;
    const int n0 = (rem & 15) * 64;
    const int tid = threadIdx.x;
    const float* s = (w == 0) ? kz : ((w == 1) ? kr : kh);

#pragma unroll
    for (int r = 0; r < 4; ++r) {
        const int kk = (tid >> 4) + r * 16;
        const int nn = (tid & 15) * 4;
        float4 v = *(const float4*)&s[(size_t)(k0 + kk) * H_DIM + n0 + nn];
        lds[kk][nn + 0] = v.x; lds[kk][nn + 1] = v.y;
        lds[kk][nn + 2] = v.z; lds[kk][nn + 3] = v.w;
    }
    __syncthreads();
#pragma unroll
    for (int r = 0; r < 4; ++r) {
        const int nr = (tid >> 4) + r * 16;
        const int kb = (tid & 15) * 4;
        half4v hi, lo;
#pragma unroll
        for (int i = 0; i < 4; ++i) {
            float v = lds[kb + i][nr];
            _Float16 h = (_Float16)v;
            hi[i] = h; lo[i] = (_Float16)(v - (float)h);
        }
        const size_t o = ((size_t)(w * H_DIM + n0 + nr)) * K_DIM + k0 + kb;
        *(half4v*)&wth[o] = hi;
        *(half4v*)&wtl[o] = lo;
    }
}

// ---------------------------------------------------------------------------
// MFMA GEMM: C[M,3072] = A[M,512] * Bt[3072,512]^T with fp16 3-term split.
// Round-0 structure verbatim: 128x128 block tile, 4 waves each 64x64.
// TR=false: outputs XZ/XR/OUT in [b][t][h] layout (old scan path).
// TR=true : outputs XZt/XRt/XHt in [b][h][t] layout; C-fragment rows are
//           t-contiguous -> float4 stores.
// ---------------------------------------------------------------------------
template<bool TR>
__global__ __launch_bounds__(256) void gemm_mfma_split(
    const _Float16* __restrict__ Ahi, const _Float16* __restrict__ Alo,
    const _Float16* __restrict__ Bthi, const _Float16* __restrict__ Btlo,
    float* __restrict__ XZ, float* __restrict__ XR, float* __restrict__ OUT)
{
    __shared__ _Float16 Ah[128 * 32];
    __shared__ _Float16 Al[128 * 32];
    __shared__ _Float16 Bh[128 * 32];
    __shared__ _Float16 Bl[128 * 32];

    const int tid = threadIdx.x;
    const int w = tid >> 6, l = tid & 63;
    const int l15 = l & 15, quad = l >> 4;
    const int bx = blockIdx.x, by = blockIdx.y;
    const long m0 = (long)by * 128;
    const long n0 = (long)bx * 128;

    f32x4 acc[4][4] = {};

    // staging: 512 16B-slots per tile, thread covers slots tid and tid+256.
    const int s1 = tid, s2 = tid + 256;
    const long aoff1 = (m0 + (s1 >> 2)) * K_DIM + (s1 & 3) * 8;
    const long aoff2 = (m0 + (s2 >> 2)) * K_DIM + (s2 & 3) * 8;
    const long boff1 = (n0 + (s1 >> 2)) * K_DIM + (s1 & 3) * 8;
    const long boff2 = (n0 + (s2 >> 2)) * K_DIM + (s2 & 3) * 8;

    const _Float16* a1 = Ahi + aoff1;  const _Float16* a2 = Ahi + aoff2;
    const _Float16* q1 = Alo + aoff1;  const _Float16* q2 = Alo + aoff2;
    const _Float16* b1 = Bthi + boff1; const _Float16* b2 = Bthi + boff2;
    const _Float16* c1 = Btlo + boff1; const _Float16* c2 = Btlo + boff2;

    _Float16* ldsA1 = &Ah[w * 512]; _Float16* ldsA2 = &Ah[2048 + w * 512];
    _Float16* ldsQ1 = &Al[w * 512]; _Float16* ldsQ2 = &Al[2048 + w * 512];
    _Float16* ldsB1 = &Bh[w * 512]; _Float16* ldsB2 = &Bh[2048 + w * 512];
    _Float16* ldsC1 = &Bl[w * 512]; _Float16* ldsC2 = &Bl[2048 + w * 512];

    const int wm = (w >> 1) * 64, wn = (w & 1) * 64;

    for (int kk = 0; kk < K_DIM / 32; ++kk) {
        load_lds16(a1, ldsA1); load_lds16(a2, ldsA2);
        load_lds16(q1, ldsQ1); load_lds16(q2, ldsQ2);
        load_lds16(b1, ldsB1); load_lds16(b2, ldsB2);
        load_lds16(c1, ldsC1); load_lds16(c2, ldsC2);
        a1 += 32; a2 += 32; q1 += 32; q2 += 32;
        b1 += 32; b2 += 32; c1 += 32; c2 += 32;
        __syncthreads();

        half8v afh[4], afl[4], bfh[4], bfl[4];
#pragma unroll
        for (int mi = 0; mi < 4; ++mi) {
            int row = (wm + mi * 16 + l15) * 32 + quad * 8;
            afh[mi] = *(const half8v*)&Ah[row];
            afl[mi] = *(const half8v*)&Al[row];
        }
#pragma unroll
        for (int ni = 0; ni < 4; ++ni) {
            int row = (wn + ni * 16 + l15) * 32 + quad * 8;
            bfh[ni] = *(const half8v*)&Bh[row];
            bfl[ni] = *(const half8v*)&Bl[row];
        }
#pragma unroll
        for (int mi = 0; mi < 4; ++mi)
#pragma unroll
            for (int ni = 0; ni < 4; ++ni) {
                acc[mi][ni] = mfma16(afh[mi], bfh[ni], acc[mi][ni]);
                acc[mi][ni] = mfma16(afh[mi], bfl[ni], acc[mi][ni]);
                acc[mi][ni] = mfma16(afl[mi], bfh[ni], acc[mi][ni]);
            }
        __syncthreads();
    }

    // Epilogue: C/D layout col=lane&15, row=quad*4+i.
    if (!TR) {
        float* dst = (bx < 8) ? XZ : ((bx < 16) ? XR : OUT);
        const long nl = (long)(bx & 7) * 128 + wn + l15;
#pragma unroll
        for (int mi = 0; mi < 4; ++mi) {
            const long m = m0 + wm + mi * 16 + quad * 4;
#pragma unroll
            for (int ni = 0; ni < 4; ++ni) {
                float* p = dst + m * H_DIM + nl + ni * 16;
#pragma unroll
                for (int i = 0; i < 4; ++i)
                    p[(long)i * H_DIM] = acc[mi][ni][i];
            }
        }
    } else {
        // Transposed [b][h][t]: rows (quad*4+i) map to consecutive t.
        float* dst = (bx < 8) ? XZ : ((bx < 16) ? XR : OUT);
#pragma unroll
        for (int mi = 0; mi < 4; ++mi) {
            const long m = m0 + wm + mi * 16 + quad * 4;
            const long b = m >> 9;          // m / 512
            const long t = m & 511;
#pragma unroll
            for (int ni = 0; ni < 4; ++ni) {
                const long n = (long)(bx & 7) * 128 + wn + ni * 16 + l15;
                *(f32x4*)&dst[((size_t)(b * H_DIM + n) << 9) + t] = acc[mi][ni];
            }
        }
    }
}

// ---------------------------------------------------------------------------
// Fallback fp32 GEMM (round 0)
// ---------------------------------------------------------------------------
#define BM 128
#define BN 128
#define BK 8
__global__ __launch_bounds__(256) void gemm_f32(
    const float* __restrict__ A, const float* __restrict__ B,
    float* __restrict__ C, int M, int N, int K)
{
    __shared__ float As[BK][BM];
    __shared__ float Bs[BK][BN];
    const int tid = threadIdx.x;
    const int bm = blockIdx.y * BM, bn = blockIdx.x * BN;
    const int tx = tid & 15, ty = tid >> 4;
    float acc[8][8];
#pragma unroll
    for (int i = 0; i < 8; i++)
#pragma unroll
        for (int j = 0; j < 8; j++) acc[i][j] = 0.f;
    const int a_row = tid >> 1, a_k = (tid & 1) * 4;
    const int b_row = tid >> 5, b_col = (tid & 31) * 4;
    const float* Aptr = A + (size_t)(bm + a_row) * K + a_k;
    const float* Bptr = B + (size_t)b_row * N + bn + b_col;
    for (int k0 = 0; k0 < K; k0 += BK) {
        float4 av = *(const float4*)(Aptr + k0);
        float4 bv = *(const float4*)(Bptr + (size_t)k0 * N);
        As[a_k + 0][a_row] = av.x; As[a_k + 1][a_row] = av.y;
        As[a_k + 2][a_row] = av.z; As[a_k + 3][a_row] = av.w;
        *(float4*)&Bs[b_row][b_col] = bv;
        __syncthreads();
#pragma unroll
        for (int kk = 0; kk < BK; kk++) {
            float4 a0 = *(const float4*)&As[kk][ty * 8];
            float4 a1 = *(const float4*)&As[kk][ty * 8 + 4];
            float4 b0 = *(const float4*)&Bs[kk][tx * 8];
            float4 b1 = *(const float4*)&Bs[kk][tx * 8 + 4];
            float a[8] = {a0.x, a0.y, a0.z, a0.w, a1.x, a1.y, a1.z, a1.w};
            float b[8] = {b0.x, b0.y, b0.z, b0.w, b1.x, b1.y, b1.z, b1.w};
#pragma unroll
            for (int i = 0; i < 8; i++)
#pragma unroll
                for (int j = 0; j < 8; j++)
                    acc[i][j] = fmaf(a[i], b[j], acc[i][j]);
        }
        __syncthreads();
    }
    float* Cptr = C + (size_t)(bm + ty * 8) * N + bn + tx * 8;
#pragma unroll
    for (int i = 0; i < 8; i++) {
        float4 c0 = {acc[i][0], acc[i][1], acc[i][2], acc[i][3]};
        float4 c1 = {acc[i][4], acc[i][5], acc[i][6], acc[i][7]};
        *(float4*)(Cptr + (size_t)i * N)     = c0;
        *(float4*)(Cptr + (size_t)i * N + 4) = c1;
    }
}

// ---------------------------------------------------------------------------
// Scan math (shared): gates in sigmoid form; divisions via v_rcp + 1 Newton.
// ---------------------------------------------------------------------------
__device__ __forceinline__ float vrcp_nr(float d) {
    float r = __builtin_amdgcn_rcpf(d);
    return r * fmaf(-d, r, 2.0f);     // Newton: r*(2 - d*r)
}

// ---------------------------------------------------------------------------
// NEW scan over transposed inputs [b][h][t]: contiguous per-thread streams,
// float4 loads with immediate offsets, 32-step prefetch depth. Per-step math
// identical to round 3. Writes out[b][t][h] (h-coalesced across threads).
// ---------------------------------------------------------------------------
__global__ __launch_bounds__(256) void scan_t(
    const float* __restrict__ XZt, const float* __restrict__ XRt,
    const float* __restrict__ XHt, float* __restrict__ out,
    const float* __restrict__ mz, const float* __restrict__ mr,
    const float* __restrict__ br, const float* __restrict__ bz)
{
    const int gid = blockIdx.x * blockDim.x + threadIdx.x;
    const int b = gid >> 10;          // H=1024
    const int h = gid & (H_DIM - 1);

    const float mzK = -mz[h];
    const float mrK = -2.0f * mr[h];
    const float bzK = -bz[h];
    const float brK = -2.0f * br[h];
    float hs = 0.f;

    const size_t sbase = ((size_t)(b * H_DIM + h)) << 9;   // *512
    const float4* pz = (const float4*)(XZt + sbase);
    const float4* pr = (const float4*)(XRt + sbase);
    const float4* ph = (const float4*)(XHt + sbase);
    float* const po = out + ((size_t)b << 19) + h;          // b*512*1024 + h

    float cz[32], cr[32], ch[32];
#pragma unroll
    for (int q = 0; q < 8; ++q) {
        float4 vz = pz[q], vr = pr[q], vh = ph[q];
        cz[q*4+0] = bzK - vz.x; cz[q*4+1] = bzK - vz.y;
        cz[q*4+2] = bzK - vz.z; cz[q*4+3] = bzK - vz.w;
        cr[q*4+0] = fmaf(-2.0f, vr.x, brK); cr[q*4+1] = fmaf(-2.0f, vr.y, brK);
        cr[q*4+2] = fmaf(-2.0f, vr.z, brK); cr[q*4+3] = fmaf(-2.0f, vr.w, brK);
        ch[q*4+0] = -2.0f * vh.x; ch[q*4+1] = -2.0f * vh.y;
        ch[q*4+2] = -2.0f * vh.z; ch[q*4+3] = -2.0f * vh.w;
    }
    for (int t0 = 0; t0 < 512; t0 += 32) {
        float4 nz4[8], nr4[8], nh4[8];
        const bool more = (t0 + 32) < 512;
        if (more) {
            const int b4 = (t0 + 32) >> 2;
#pragma unroll
            for (int q = 0; q < 8; ++q) {
                nz4[q] = pz[b4 + q]; nr4[q] = pr[b4 + q]; nh4[q] = ph[b4 + q];
            }
        }
        float* pout = po + ((size_t)t0 << 10);
#pragma unroll
        for (int j = 0; j < 32; ++j) {
            const float u1   = fmaf(hs, mrK, cr[j]);
            const float uz   = fmaf(hs, mzK, cz[j]);
            const float hsK2 = -4.0f * hs;
            const float e1 = __expf(u1);
            const float s1 = vrcp_nr(e1 + 1.0f);
            const float ez = __expf(uz);
            const float sz = vrcp_nr(ez + 1.0f);
            const float u2 = fmaf(s1, hsK2, ch[j]);
            const float e2 = __expf(u2);
            const float s2 = vrcp_nr(e2 + 1.0f);
            const float th = fmaf(2.0f, s2, -1.0f);
            const float hn = fmaf(sz, hs - th, th);
            *pout = hn; pout += H_DIM;
            hs = hn;
        }
        if (more) {
#pragma unroll
            for (int q = 0; q < 8; ++q) {
                cz[q*4+0] = bzK - nz4[q].x; cz[q*4+1] = bzK - nz4[q].y;
                cz[q*4+2] = bzK - nz4[q].z; cz[q*4+3] = bzK - nz4[q].w;
                cr[q*4+0] = fmaf(-2.0f, nr4[q].x, brK);
                cr[q*4+1] = fmaf(-2.0f, nr4[q].y, brK);
                cr[q*4+2] = fmaf(-2.0f, nr4[q].z, brK);
                cr[q*4+3] = fmaf(-2.0f, nr4[q].w, brK);
                ch[q*4+0] = -2.0f * nh4[q].x; ch[q*4+1] = -2.0f * nh4[q].y;
                ch[q*4+2] = -2.0f * nh4[q].z; ch[q*4+3] = -2.0f * nh4[q].w;
            }
        }
    }
}

// ---------------------------------------------------------------------------
// OLD scan (round 3), kept for the mid-tier workspace path.
// ---------------------------------------------------------------------------
__global__ __launch_bounds__(256) void scan_kernel(
    const float* __restrict__ XZ, const float* __restrict__ XR,
    float* __restrict__ OUT,
    const float* __restrict__ mz, const float* __restrict__ mr,
    const float* __restrict__ br, const float* __restrict__ bz)
{
    const int gid = blockIdx.x * blockDim.x + threadIdx.x;
    const int b = gid >> 10;
    const int h = gid & (H_DIM - 1);

    const float mzK = -mz[h];
    const float mrK = -2.0f * mr[h];
    const float bzK = -bz[h];
    const float brK = -2.0f * br[h];
    float hs = 0.f;
    size_t idx = (size_t)b * 512 * H_DIM + h;

    float cz[16], cr[16], ch[16];
#pragma unroll
    for (int j = 0; j < 16; ++j) {
        cz[j] = bzK - XZ[idx + (size_t)j * H_DIM];
        cr[j] = fmaf(-2.0f, XR[idx + (size_t)j * H_DIM], brK);
        ch[j] = -2.0f * OUT[idx + (size_t)j * H_DIM];
    }
    for (int t0 = 0; t0 < 512; t0 += 16) {
        float nz[16], nr[16], nh[16];
        const bool more = (t0 + 16) < 512;
        const size_t nidx = idx + 16ul * H_DIM;
        if (more) {
#pragma unroll
            for (int j = 0; j < 16; ++j) {
                nz[j] = XZ[nidx + (size_t)j * H_DIM];
                nr[j] = XR[nidx + (size_t)j * H_DIM];
                nh[j] = OUT[nidx + (size_t)j * H_DIM];
            }
        }
#pragma unroll
        for (int j = 0; j < 16; ++j) {
            const float u1   = fmaf(hs, mrK, cr[j]);
            const float uz   = fmaf(hs, mzK, cz[j]);
            const float hsK2 = -4.0f * hs;
            const float e1 = __expf(u1);
            const float s1 = vrcp_nr(e1 + 1.0f);
            const float ez = __expf(uz);
            const float sz = vrcp_nr(ez + 1.0f);
            const float u2 = fmaf(s1, hsK2, ch[j]);
            const float e2 = __expf(u2);
            const float s2 = vrcp_nr(e2 + 1.0f);
            const float th = fmaf(2.0f, s2, -1.0f);
            const float hn = fmaf(sz, hs - th, th);
            OUT[idx + (size_t)j * H_DIM] = hn;
            hs = hn;
        }
        idx = nidx;
        if (more) {
#pragma unroll
            for (int j = 0; j < 16; ++j) {
                cz[j] = bzK - nz[j];
                cr[j] = fmaf(-2.0f, nr[j], brK);
                ch[j] = -2.0f * nh[j];
            }
        }
    }
}

// ---------------------------------------------------------------------------
extern "C" void kernel_launch(void* const* d_in, const int* in_sizes, int n_in,
                              void* d_out, int out_size, void* d_ws, size_t ws_size,
                              hipStream_t stream) {
    const float* x  = (const float*)d_in[0];
    const float* kz = (const float*)d_in[1];
    const float* kr = (const float*)d_in[2];
    const float* kh = (const float*)d_in[3];
    const float* mz = (const float*)d_in[4];
    const float* mr = (const float*)d_in[5];
    const float* br = (const float*)d_in[6];
    const float* bz = (const float*)d_in[7];
    float* out = (float*)d_out;

    char* ws = (char*)d_ws;
    const int n4 = M_DIM * K_DIM / 4;

    // --- new (transposed-scan) layout: 454 MiB ---
    const size_t need_t = 476053504ul;
    // --- old layout: 326 MiB ---
    const size_t need_o = 341835776ul;

    if (ws_size >= need_t) {
        float* XZt = (float*)ws;                               // 128 MiB
        float* XRt = (float*)(ws + 134217728ul);               // 128 MiB
        float* XHt = (float*)(ws + 268435456ul);               // 128 MiB
        _Float16* XHI = (_Float16*)(ws + 402653184ul);         // 32 MiB
        _Float16* XLO = (_Float16*)(ws + 436207616ul);         // 32 MiB
        _Float16* WTH = (_Float16*)(ws + 469762048ul);         // 3 MiB
        _Float16* WTL = (_Float16*)(ws + 472907776ul);         // 3 MiB

        convert_x<<<n4 / 256, 256, 0, stream>>>(
            (const float4*)x, (half4v*)XHI, (half4v*)XLO, n4);
        convert_wt_t<<<384, 256, 0, stream>>>(kz, kr, kh, WTH, WTL);
        dim3 grid(N3 / 128, M_DIM / 128);                      // 24 x 256
        gemm_mfma_split<true><<<grid, 256, 0, stream>>>(
            XHI, XLO, WTH, WTL, XZt, XRt, XHt);
        scan_t<<<(64 * H_DIM) / 256, 256, 0, stream>>>(
            XZt, XRt, XHt, out, mz, mr, br, bz);
    } else if (ws_size >= need_o) {
        float* XZ = (float*)ws;                                // 128 MiB
        float* XR = (float*)(ws + 134217728ul);                // 128 MiB
        _Float16* XHI = (_Float16*)(ws + 268435456ul);         // 32 MiB
        _Float16* XLO = (_Float16*)(ws + 301989888ul);         // 32 MiB
        _Float16* WTH = (_Float16*)(ws + 335544320ul);         // 3 MiB
        _Float16* WTL = (_Float16*)(ws + 338690048ul);         // 3 MiB

        convert_x<<<n4 / 256, 256, 0, stream>>>(
            (const float4*)x, (half4v*)XHI, (half4v*)XLO, n4);
        convert_wt_t<<<384, 256, 0, stream>>>(kz, kr, kh, WTH, WTL);
        dim3 grid(N3 / 128, M_DIM / 128);
        gemm_mfma_split<false><<<grid, 256, 0, stream>>>(
            XHI, XLO, WTH, WTL, XZ, XR, out);
        scan_kernel<<<(64 * H_DIM) / 256, 256, 0, stream>>>(
            XZ, XR, out, mz, mr, br, bz);
    } else {
        float* XZ = (float*)ws;
        float* XR = (float*)(ws + 134217728ul);
        dim3 grid(H_DIM / BN, M_DIM / BM);
        gemm_f32<<<grid, 256, 0, stream>>>(x, kz, XZ,  M_DIM, H_DIM, K_DIM);
        gemm_f32<<<grid, 256, 0, stream>>>(x, kr, XR,  M_DIM, H_DIM, K_DIM);
        gemm_f32<<<grid, 256, 0, stream>>>(x, kh, out, M_DIM, H_DIM, K_DIM);
        scan_kernel<<<(64 * H_DIM) / 256, 256, 0, stream>>>(
            XZ, XR, out, mz, mr, br, bz);
    }
}

// Round 6
// 587.297 us; speedup vs baseline: 1.0600x; 1.0243x over previous
//
#include <hip/hip_runtime.h>
#include <hip/hip_bf16.h>
#include <math.h>

// ---------------------------------------------------------------------------
// GRU-like cell. B=64, T=512, D=512, H=1024 (fp32).
// Round 7:
//   * Theory: scan is capped at ~1/3 BW by HBM channel aliasing from exact
//     4096-B strides ([b][t][1024] fp32). Intermediates XZ/XR/XH now stored
//     with PADDED row stride 1088 floats (4352 B = 17*256) -> successive
//     t-steps rotate across channels. Output write stays [B,T,1024].
//   * GEMM: round-0 structure verbatim (best measured, 303 us); epilogue
//     h-coalesced scalar stores at stride 1088 (TR epilogue reverted: +16us).
//   * Scan: round-3 math bit-identical (rcp+NR sigmoid forms, absmax 2^-8),
//     h-coalesced reads from padded arrays, 16-step prefetch.
// Precision: 3-term fp16 split GEMM and fp32 scan math unchanged.
// ---------------------------------------------------------------------------

#define M_DIM 32768   // B*T
#define K_DIM 512     // D
#define H_DIM 1024
#define HPAD  1088    // padded row stride (floats) = 4352 B, breaks 4KB alias
#define N3    3072    // 3*H

typedef _Float16 half8v __attribute__((ext_vector_type(8)));
typedef _Float16 half4v __attribute__((ext_vector_type(4)));
typedef float f32x4 __attribute__((ext_vector_type(4)));

__device__ __forceinline__ f32x4 mfma16(half8v a, half8v b, f32x4 c) {
    return __builtin_amdgcn_mfma_f32_16x16x32_f16(a, b, c, 0, 0, 0);
}

__device__ __forceinline__ void load_lds16(const void* g, void* l) {
    __builtin_amdgcn_global_load_lds(
        (const __attribute__((address_space(1))) void*)g,
        (__attribute__((address_space(3))) void*)l, 16, 0, 0);
}

// ---------------------------------------------------------------------------
// Conversion: x [M,K] fp32 -> xhi/xlo fp16 (same layout), via float4.
// ---------------------------------------------------------------------------
__global__ __launch_bounds__(256) void convert_x(
    const float4* __restrict__ x4, half4v* __restrict__ hi4,
    half4v* __restrict__ lo4, int n4)
{
    int i = blockIdx.x * 256 + threadIdx.x;
    if (i >= n4) return;
    float4 v = x4[i];
    half4v h, lo;
    h.x = (_Float16)v.x; lo.x = (_Float16)(v.x - (float)h.x);
    h.y = (_Float16)v.y; lo.y = (_Float16)(v.y - (float)h.y);
    h.z = (_Float16)v.z; lo.z = (_Float16)(v.z - (float)h.z);
    h.w = (_Float16)v.w; lo.w = (_Float16)(v.w - (float)h.w);
    hi4[i] = h; lo4[i] = lo;
}

// ---------------------------------------------------------------------------
// Weights [K,1024] fp32 -> transposed hi/lo fp16 [3][1024][512].
// LDS-tiled 64x64 transpose: coalesced reads AND writes.
// ---------------------------------------------------------------------------
__global__ __launch_bounds__(256) void convert_wt_t(
    const float* __restrict__ kz, const float* __restrict__ kr,
    const float* __restrict__ kh, _Float16* __restrict__ wth,
    _Float16* __restrict__ wtl)
{
    __shared__ float lds[64][65];
    const int bid = blockIdx.x;          // 3 * 8 * 16 = 384
    const int w = bid >> 7;              // weight select
    const int rem = bid & 127;
    const int k0 = (rem >> 4) * 64;
    const int n0 = (rem & 15) * 64;
    const int tid = threadIdx.x;
    const float* s = (w == 0) ? kz : ((w == 1) ? kr : kh);

#pragma unroll
    for (int r = 0; r < 4; ++r) {
        const int kk = (tid >> 4) + r * 16;
        const int nn = (tid & 15) * 4;
        float4 v = *(const float4*)&s[(size_t)(k0 + kk) * H_DIM + n0 + nn];
        lds[kk][nn + 0] = v.x; lds[kk][nn + 1] = v.y;
        lds[kk][nn + 2] = v.z; lds[kk][nn + 3] = v.w;
    }
    __syncthreads();
#pragma unroll
    for (int r = 0; r < 4; ++r) {
        const int nr = (tid >> 4) + r * 16;
        const int kb = (tid & 15) * 4;
        half4v hi, lo;
#pragma unroll
        for (int i = 0; i < 4; ++i) {
            float v = lds[kb + i][nr];
            _Float16 h = (_Float16)v;
            hi[i] = h; lo[i] = (_Float16)(v - (float)h);
        }
        const size_t o = ((size_t)(w * H_DIM + n0 + nr)) * K_DIM + k0 + kb;
        *(half4v*)&wth[o] = hi;
        *(half4v*)&wtl[o] = lo;
    }
}

// ---------------------------------------------------------------------------
// MFMA GEMM: C[M,3072] = A[M,512] * Bt[3072,512]^T with fp16 3-term split.
// Round-0 structure verbatim: 128x128 block tile, 4 waves each 64x64.
// PAD=true : stores to XZ/XR/XH with row stride HPAD (scan intermediates).
// PAD=false: stores to XZ/XR/OUT with row stride H_DIM (mid-tier path).
// ---------------------------------------------------------------------------
template<bool PAD>
__global__ __launch_bounds__(256) void gemm_mfma_split(
    const _Float16* __restrict__ Ahi, const _Float16* __restrict__ Alo,
    const _Float16* __restrict__ Bthi, const _Float16* __restrict__ Btlo,
    float* __restrict__ XZ, float* __restrict__ XR, float* __restrict__ OUT)
{
    __shared__ _Float16 Ah[128 * 32];
    __shared__ _Float16 Al[128 * 32];
    __shared__ _Float16 Bh[128 * 32];
    __shared__ _Float16 Bl[128 * 32];

    const int tid = threadIdx.x;
    const int w = tid >> 6, l = tid & 63;
    const int l15 = l & 15, quad = l >> 4;
    const int bx = blockIdx.x, by = blockIdx.y;
    const long m0 = (long)by * 128;
    const long n0 = (long)bx * 128;

    f32x4 acc[4][4] = {};

    // staging: 512 16B-slots per tile, thread covers slots tid and tid+256.
    const int s1 = tid, s2 = tid + 256;
    const long aoff1 = (m0 + (s1 >> 2)) * K_DIM + (s1 & 3) * 8;
    const long aoff2 = (m0 + (s2 >> 2)) * K_DIM + (s2 & 3) * 8;
    const long boff1 = (n0 + (s1 >> 2)) * K_DIM + (s1 & 3) * 8;
    const long boff2 = (n0 + (s2 >> 2)) * K_DIM + (s2 & 3) * 8;

    const _Float16* a1 = Ahi + aoff1;  const _Float16* a2 = Ahi + aoff2;
    const _Float16* q1 = Alo + aoff1;  const _Float16* q2 = Alo + aoff2;
    const _Float16* b1 = Bthi + boff1; const _Float16* b2 = Bthi + boff2;
    const _Float16* c1 = Btlo + boff1; const _Float16* c2 = Btlo + boff2;

    _Float16* ldsA1 = &Ah[w * 512]; _Float16* ldsA2 = &Ah[2048 + w * 512];
    _Float16* ldsQ1 = &Al[w * 512]; _Float16* ldsQ2 = &Al[2048 + w * 512];
    _Float16* ldsB1 = &Bh[w * 512]; _Float16* ldsB2 = &Bh[2048 + w * 512];
    _Float16* ldsC1 = &Bl[w * 512]; _Float16* ldsC2 = &Bl[2048 + w * 512];

    const int wm = (w >> 1) * 64, wn = (w & 1) * 64;

    for (int kk = 0; kk < K_DIM / 32; ++kk) {
        load_lds16(a1, ldsA1); load_lds16(a2, ldsA2);
        load_lds16(q1, ldsQ1); load_lds16(q2, ldsQ2);
        load_lds16(b1, ldsB1); load_lds16(b2, ldsB2);
        load_lds16(c1, ldsC1); load_lds16(c2, ldsC2);
        a1 += 32; a2 += 32; q1 += 32; q2 += 32;
        b1 += 32; b2 += 32; c1 += 32; c2 += 32;
        __syncthreads();

        half8v afh[4], afl[4], bfh[4], bfl[4];
#pragma unroll
        for (int mi = 0; mi < 4; ++mi) {
            int row = (wm + mi * 16 + l15) * 32 + quad * 8;
            afh[mi] = *(const half8v*)&Ah[row];
            afl[mi] = *(const half8v*)&Al[row];
        }
#pragma unroll
        for (int ni = 0; ni < 4; ++ni) {
            int row = (wn + ni * 16 + l15) * 32 + quad * 8;
            bfh[ni] = *(const half8v*)&Bh[row];
            bfl[ni] = *(const half8v*)&Bl[row];
        }
#pragma unroll
        for (int mi = 0; mi < 4; ++mi)
#pragma unroll
            for (int ni = 0; ni < 4; ++ni) {
                acc[mi][ni] = mfma16(afh[mi], bfh[ni], acc[mi][ni]);
                acc[mi][ni] = mfma16(afh[mi], bfl[ni], acc[mi][ni]);
                acc[mi][ni] = mfma16(afl[mi], bfh[ni], acc[mi][ni]);
            }
        __syncthreads();
    }

    // Epilogue: C/D layout col=lane&15, row=quad*4+i. h-coalesced stores.
    const long stride = PAD ? HPAD : H_DIM;
    float* dst = (bx < 8) ? XZ : ((bx < 16) ? XR : OUT);
    const long nl = (long)(bx & 7) * 128 + wn + l15;
#pragma unroll
    for (int mi = 0; mi < 4; ++mi) {
        const long m = m0 + wm + mi * 16 + quad * 4;
#pragma unroll
        for (int ni = 0; ni < 4; ++ni) {
            float* p = dst + m * stride + nl + ni * 16;
#pragma unroll
            for (int i = 0; i < 4; ++i)
                p[(long)i * stride] = acc[mi][ni][i];
        }
    }
}

// ---------------------------------------------------------------------------
// Fallback fp32 GEMM (round 0)
// ---------------------------------------------------------------------------
#define BM 128
#define BN 128
#define BK 8
__global__ __launch_bounds__(256) void gemm_f32(
    const float* __restrict__ A, const float* __restrict__ B,
    float* __restrict__ C, int M, int N, int K)
{
    __shared__ float As[BK][BM];
    __shared__ float Bs[BK][BN];
    const int tid = threadIdx.x;
    const int bm = blockIdx.y * BM, bn = blockIdx.x * BN;
    const int tx = tid & 15, ty = tid >> 4;
    float acc[8][8];
#pragma unroll
    for (int i = 0; i < 8; i++)
#pragma unroll
        for (int j = 0; j < 8; j++) acc[i][j] = 0.f;
    const int a_row = tid >> 1, a_k = (tid & 1) * 4;
    const int b_row = tid >> 5, b_col = (tid & 31) * 4;
    const float* Aptr = A + (size_t)(bm + a_row) * K + a_k;
    const float* Bptr = B + (size_t)b_row * N + bn + b_col;
    for (int k0 = 0; k0 < K; k0 += BK) {
        float4 av = *(const float4*)(Aptr + k0);
        float4 bv = *(const float4*)(Bptr + (size_t)k0 * N);
        As[a_k + 0][a_row] = av.x; As[a_k + 1][a_row] = av.y;
        As[a_k + 2][a_row] = av.z; As[a_k + 3][a_row] = av.w;
        *(float4*)&Bs[b_row][b_col] = bv;
        __syncthreads();
#pragma unroll
        for (int kk = 0; kk < BK; kk++) {
            float4 a0 = *(const float4*)&As[kk][ty * 8];
            float4 a1 = *(const float4*)&As[kk][ty * 8 + 4];
            float4 b0 = *(const float4*)&Bs[kk][tx * 8];
            float4 b1 = *(const float4*)&Bs[kk][tx * 8 + 4];
            float a[8] = {a0.x, a0.y, a0.z, a0.w, a1.x, a1.y, a1.z, a1.w};
            float b[8] = {b0.x, b0.y, b0.z, b0.w, b1.x, b1.y, b1.z, b1.w};
#pragma unroll
            for (int i = 0; i < 8; i++)
#pragma unroll
                for (int j = 0; j < 8; j++)
                    acc[i][j] = fmaf(a[i], b[j], acc[i][j]);
        }
        __syncthreads();
    }
    float* Cptr = C + (size_t)(bm + ty * 8) * N + bn + tx * 8;
#pragma unroll
    for (int i = 0; i < 8; i++) {
        float4 c0 = {acc[i][0], acc[i][1], acc[i][2], acc[i][3]};
        float4 c1 = {acc[i][4], acc[i][5], acc[i][6], acc[i][7]};
        *(float4*)(Cptr + (size_t)i * N)     = c0;
        *(float4*)(Cptr + (size_t)i * N + 4) = c1;
    }
}

// ---------------------------------------------------------------------------
// Scan math (shared): gates in sigmoid form; divisions via v_rcp + 1 Newton.
// ---------------------------------------------------------------------------
__device__ __forceinline__ float vrcp_nr(float d) {
    float r = __builtin_amdgcn_rcpf(d);
    return r * fmaf(-d, r, 2.0f);     // Newton: r*(2 - d*r)
}

// ---------------------------------------------------------------------------
// Scan over padded intermediates [b][t][HPAD] (reads) -> out [b][t][H_DIM].
// h-coalesced across lanes, 16-step prefetch. Math identical to round 3.
// ---------------------------------------------------------------------------
__global__ __launch_bounds__(256) void scan_pad(
    const float* __restrict__ XZ, const float* __restrict__ XR,
    const float* __restrict__ XH, float* __restrict__ out,
    const float* __restrict__ mz, const float* __restrict__ mr,
    const float* __restrict__ br, const float* __restrict__ bz)
{
    const int gid = blockIdx.x * blockDim.x + threadIdx.x;
    const int b = gid >> 10;          // H=1024
    const int h = gid & (H_DIM - 1);

    const float mzK = -mz[h];
    const float mrK = -2.0f * mr[h];
    const float bzK = -bz[h];
    const float brK = -2.0f * br[h];
    float hs = 0.f;
    size_t ri = (size_t)b * 512 * HPAD + h;       // padded read index
    size_t wi = (size_t)b * 512 * H_DIM + h;      // output write index

    float cz[16], cr[16], ch[16];
#pragma unroll
    for (int j = 0; j < 16; ++j) {
        cz[j] = bzK - XZ[ri + (size_t)j * HPAD];
        cr[j] = fmaf(-2.0f, XR[ri + (size_t)j * HPAD], brK);
        ch[j] = -2.0f * XH[ri + (size_t)j * HPAD];
    }
    for (int t0 = 0; t0 < 512; t0 += 16) {
        float nz[16], nr[16], nh[16];
        const bool more = (t0 + 16) < 512;
        const size_t nri = ri + 16ul * HPAD;
        if (more) {
#pragma unroll
            for (int j = 0; j < 16; ++j) {
                nz[j] = XZ[nri + (size_t)j * HPAD];
                nr[j] = XR[nri + (size_t)j * HPAD];
                nh[j] = XH[nri + (size_t)j * HPAD];
            }
        }
#pragma unroll
        for (int j = 0; j < 16; ++j) {
            const float u1   = fmaf(hs, mrK, cr[j]);
            const float uz   = fmaf(hs, mzK, cz[j]);
            const float hsK2 = -4.0f * hs;
            const float e1 = __expf(u1);
            const float s1 = vrcp_nr(e1 + 1.0f);
            const float ez = __expf(uz);
            const float sz = vrcp_nr(ez + 1.0f);
            const float u2 = fmaf(s1, hsK2, ch[j]);
            const float e2 = __expf(u2);
            const float s2 = vrcp_nr(e2 + 1.0f);
            const float th = fmaf(2.0f, s2, -1.0f);
            const float hn = fmaf(sz, hs - th, th);
            out[wi + (size_t)j * H_DIM] = hn;
            hs = hn;
        }
        ri = nri;
        wi += 16ul * H_DIM;
        if (more) {
#pragma unroll
            for (int j = 0; j < 16; ++j) {
                cz[j] = bzK - nz[j];
                cr[j] = fmaf(-2.0f, nr[j], brK);
                ch[j] = -2.0f * nh[j];
            }
        }
    }
}

// ---------------------------------------------------------------------------
// OLD scan (round 3), unpadded in-place variant for the mid-tier path.
// ---------------------------------------------------------------------------
__global__ __launch_bounds__(256) void scan_kernel(
    const float* __restrict__ XZ, const float* __restrict__ XR,
    float* __restrict__ OUT,
    const float* __restrict__ mz, const float* __restrict__ mr,
    const float* __restrict__ br, const float* __restrict__ bz)
{
    const int gid = blockIdx.x * blockDim.x + threadIdx.x;
    const int b = gid >> 10;
    const int h = gid & (H_DIM - 1);

    const float mzK = -mz[h];
    const float mrK = -2.0f * mr[h];
    const float bzK = -bz[h];
    const float brK = -2.0f * br[h];
    float hs = 0.f;
    size_t idx = (size_t)b * 512 * H_DIM + h;

    float cz[16], cr[16], ch[16];
#pragma unroll
    for (int j = 0; j < 16; ++j) {
        cz[j] = bzK - XZ[idx + (size_t)j * H_DIM];
        cr[j] = fmaf(-2.0f, XR[idx + (size_t)j * H_DIM], brK);
        ch[j] = -2.0f * OUT[idx + (size_t)j * H_DIM];
    }
    for (int t0 = 0; t0 < 512; t0 += 16) {
        float nz[16], nr[16], nh[16];
        const bool more = (t0 + 16) < 512;
        const size_t nidx = idx + 16ul * H_DIM;
        if (more) {
#pragma unroll
            for (int j = 0; j < 16; ++j) {
                nz[j] = XZ[nidx + (size_t)j * H_DIM];
                nr[j] = XR[nidx + (size_t)j * H_DIM];
                nh[j] = OUT[nidx + (size_t)j * H_DIM];
            }
        }
#pragma unroll
        for (int j = 0; j < 16; ++j) {
            const float u1   = fmaf(hs, mrK, cr[j]);
            const float uz   = fmaf(hs, mzK, cz[j]);
            const float hsK2 = -4.0f * hs;
            const float e1 = __expf(u1);
            const float s1 = vrcp_nr(e1 + 1.0f);
            const float ez = __expf(uz);
            const float sz = vrcp_nr(ez + 1.0f);
            const float u2 = fmaf(s1, hsK2, ch[j]);
            const float e2 = __expf(u2);
            const float s2 = vrcp_nr(e2 + 1.0f);
            const float th = fmaf(2.0f, s2, -1.0f);
            const float hn = fmaf(sz, hs - th, th);
            OUT[idx + (size_t)j * H_DIM] = hn;
            hs = hn;
        }
        idx = nidx;
        if (more) {
#pragma unroll
            for (int j = 0; j < 16; ++j) {
                cz[j] = bzK - nz[j];
                cr[j] = fmaf(-2.0f, nr[j], brK);
                ch[j] = -2.0f * nh[j];
            }
        }
    }
}

// ---------------------------------------------------------------------------
extern "C" void kernel_launch(void* const* d_in, const int* in_sizes, int n_in,
                              void* d_out, int out_size, void* d_ws, size_t ws_size,
                              hipStream_t stream) {
    const float* x  = (const float*)d_in[0];
    const float* kz = (const float*)d_in[1];
    const float* kr = (const float*)d_in[2];
    const float* kh = (const float*)d_in[3];
    const float* mz = (const float*)d_in[4];
    const float* mr = (const float*)d_in[5];
    const float* br = (const float*)d_in[6];
    const float* bz = (const float*)d_in[7];
    float* out = (float*)d_out;

    char* ws = (char*)d_ws;
    const int n4 = M_DIM * K_DIM / 4;

    const size_t PARR = (size_t)M_DIM * HPAD * 4ul;        // 142,606,336 B
    const size_t need_pad = 3ul * PARR + 67108864ul + 6291456ul; // ~478 MiB
    const size_t need_o   = 341835776ul;                    // round-3 layout

    if (ws_size >= need_pad) {
        float* XZ = (float*)ws;
        float* XR = (float*)(ws + PARR);
        float* XH = (float*)(ws + 2 * PARR);
        _Float16* XHI = (_Float16*)(ws + 3 * PARR);
        _Float16* XLO = (_Float16*)(ws + 3 * PARR + 33554432ul);
        _Float16* WTH = (_Float16*)(ws + 3 * PARR + 67108864ul);
        _Float16* WTL = (_Float16*)(ws + 3 * PARR + 70254592ul);

        convert_x<<<n4 / 256, 256, 0, stream>>>(
            (const float4*)x, (half4v*)XHI, (half4v*)XLO, n4);
        convert_wt_t<<<384, 256, 0, stream>>>(kz, kr, kh, WTH, WTL);
        dim3 grid(N3 / 128, M_DIM / 128);                  // 24 x 256
        gemm_mfma_split<true><<<grid, 256, 0, stream>>>(
            XHI, XLO, WTH, WTL, XZ, XR, XH);
        scan_pad<<<(64 * H_DIM) / 256, 256, 0, stream>>>(
            XZ, XR, XH, out, mz, mr, br, bz);
    } else if (ws_size >= need_o) {
        float* XZ = (float*)ws;                            // 128 MiB
        float* XR = (float*)(ws + 134217728ul);            // 128 MiB
        _Float16* XHI = (_Float16*)(ws + 268435456ul);     // 32 MiB
        _Float16* XLO = (_Float16*)(ws + 301989888ul);     // 32 MiB
        _Float16* WTH = (_Float16*)(ws + 335544320ul);     // 3 MiB
        _Float16* WTL = (_Float16*)(ws + 338690048ul);     // 3 MiB

        convert_x<<<n4 / 256, 256, 0, stream>>>(
            (const float4*)x, (half4v*)XHI, (half4v*)XLO, n4);
        convert_wt_t<<<384, 256, 0, stream>>>(kz, kr, kh, WTH, WTL);
        dim3 grid(N3 / 128, M_DIM / 128);
        gemm_mfma_split<false><<<grid, 256, 0, stream>>>(
            XHI, XLO, WTH, WTL, XZ, XR, out);
        scan_kernel<<<(64 * H_DIM) / 256, 256, 0, stream>>>(
            XZ, XR, out, mz, mr, br, bz);
    } else {
        float* XZ = (float*)ws;
        float* XR = (float*)(ws + 134217728ul);
        dim3 grid(H_DIM / BN, M_DIM / BM);
        gemm_f32<<<grid, 256, 0, stream>>>(x, kz, XZ,  M_DIM, H_DIM, K_DIM);
        gemm_f32<<<grid, 256, 0, stream>>>(x, kr, XR,  M_DIM, H_DIM, K_DIM);
        gemm_f32<<<grid, 256, 0, stream>>>(x, kh, out, M_DIM, H_DIM, K_DIM);
        scan_kernel<<<(64 * H_DIM) / 256, 256, 0, stream>>>(
            XZ, XR, out, mz, mr, br, bz);
    }
}